// Round 3
// baseline (895.244 us; speedup 1.0000x reference)
//
#include <hip/hip_runtime.h>
#include <math.h>

#define B_ 8
#define T_ 1000
#define C_ 8
#define F_ 513
#define ATT_ 320
#define BF_ (B_*F_)          // 4104
#define FT 64
#define NFT 9
#define TCH 8

// ---------------- Kernel 1: masked PSD accumulation ----------------
// grid (NFT, nsplit, B), block 256.
// Accumulates, per (b,f): psd[c,e] = sum_t w[t] x[c,t] conj(x[e,t]) for both masks,
// with w[t] = mean_c mask[b,f,c,t], unnormalized (normalization folded into k2a/k3:
// the MVDR solve/trace path is scale-invariant; only the attention feature needs /S).
// 36 unique Hermitian pairs split over 4 thread-groups of 9 pairs; 64 freqs/block.
// TL (time per split) is always divisible by 4 -> float4 mask loads stay 16B aligned.
__global__ __launch_bounds__(256) void k1_psd(
    const float* __restrict__ dre, const float* __restrict__ dim_,
    const float* __restrict__ mss, const float* __restrict__ msn,
    float* __restrict__ psdPart, float* __restrict__ ssPart, int TL)
{
    const int ft = blockIdx.x, sp = blockIdx.y, b = blockIdx.z;
    const int tid = threadIdx.x;
    const int f0 = ft * FT;
    const int t0 = sp * TL;

    __shared__ float2 xs[TCH * C_ * FT];    // [t][c][fl] complex, 32 KB
    __shared__ float  msh[2 * TCH * FT];    // [s][t][fl], 4 KB
    __shared__ float  sred[256];

    // mask persona: tid<128 -> speech, else noise; f=(tid&127)>>1, t-quad=(tid&1)*4
    const int mf = (tid & 127) >> 1;
    const int tq4 = (tid & 1) * 4;
    const int smask = tid >> 7;
    const bool fvm = (f0 + mf) < F_;
    const float* __restrict__ mp0 =
        (smask == 0 ? mss : msn) + (size_t)((b * F_ + f0 + mf) * C_) * T_ + t0;

    // data staging / compute persona
    const int fl = tid & 63, g = tid >> 6;
    const bool fvc = (f0 + fl) < F_;
    const size_t dbase0 = (size_t)(b * T_ + t0) * (C_ * F_) + f0 + fl;

    float aSr[9], aSi[9], aNr[9], aNi[9];
#pragma unroll
    for (int i = 0; i < 9; ++i) { aSr[i]=0.f; aSi[i]=0.f; aNr[i]=0.f; aNi[i]=0.f; }
    float sS = 0.f;

    for (int ch = 0; ch * TCH < TL; ++ch) {
        // ---- stage masks (channel-mean), float4 over time ----
        {
            float a4[4] = {0.f, 0.f, 0.f, 0.f};
            int tcb = ch * TCH + tq4;
            if (fvm && tcb < TL) {
                const float* mp = mp0 + tcb;
#pragma unroll
                for (int c = 0; c < C_; ++c) {
                    float4 v = *(const float4*)&mp[c * T_];
                    a4[0] += v.x; a4[1] += v.y; a4[2] += v.z; a4[3] += v.w;
                }
            }
            float lsum = 0.f;
#pragma unroll
            for (int i = 0; i < 4; ++i) {
                float mv = a4[i] * 0.125f;
                msh[smask * (TCH * FT) + (tq4 + i) * FT + mf] = mv;
                lsum += mv;
            }
            if (smask) lsum = 0.f;      // only speech mask feeds the time-sum
            sS += lsum;
        }
        // ---- stage data (lanes over f -> coalesced 256B/wave) ----
        {
#pragma unroll
            for (int t = 0; t < TCH; ++t) {
                int tc = ch * TCH + t;
                bool tv = (tc < TL) && fvc;
                size_t base = dbase0 + (size_t)tc * (C_ * F_);
#pragma unroll
                for (int cp = 0; cp < 2; ++cp) {
                    int c = g + cp * 4;
                    float vr = 0.f, vi = 0.f;
                    if (tv) { vr = dre[base + c * F_]; vi = dim_[base + c * F_]; }
                    xs[(t * C_ + c) * FT + fl] = make_float2(vr, vi);
                }
            }
        }
        __syncthreads();
        // ---- accumulate outer products ----
        for (int t = 0; t < TCH; ++t) {
            float m_s = msh[t * FT + fl], m_n = msh[TCH * FT + t * FT + fl];
            float xr[8], xi[8];
#pragma unroll
            for (int c = 0; c < 8; ++c) { float2 v = xs[(t * C_ + c) * FT + fl]; xr[c] = v.x; xi[c] = v.y; }
#define PAIR(i,c,e) { float pr = xr[c]*xr[e] + xi[c]*xi[e]; \
                      float pi = xi[c]*xr[e] - xr[c]*xi[e]; \
                      aSr[i] += m_s*pr; aSi[i] += m_s*pi;   \
                      aNr[i] += m_n*pr; aNi[i] += m_n*pi; }
            if (g == 0)      { PAIR(0,0,0) PAIR(1,0,1) PAIR(2,0,2) PAIR(3,0,3) PAIR(4,0,4) PAIR(5,0,5) PAIR(6,0,6) PAIR(7,0,7) PAIR(8,1,1) }
            else if (g == 1) { PAIR(0,1,2) PAIR(1,1,3) PAIR(2,1,4) PAIR(3,1,5) PAIR(4,1,6) PAIR(5,1,7) PAIR(6,2,2) PAIR(7,2,3) PAIR(8,2,4) }
            else if (g == 2) { PAIR(0,2,5) PAIR(1,2,6) PAIR(2,2,7) PAIR(3,3,3) PAIR(4,3,4) PAIR(5,3,5) PAIR(6,3,6) PAIR(7,3,7) PAIR(8,4,4) }
            else             { PAIR(0,4,5) PAIR(1,4,6) PAIR(2,4,7) PAIR(3,5,5) PAIR(4,5,6) PAIR(5,5,7) PAIR(6,6,6) PAIR(7,6,7) PAIR(8,7,7) }
#undef PAIR
        }
        __syncthreads();
    }

    // ---- write partials (lanes over f -> coalesced) ----
    if (fvc) {
        int base = ((((sp * B_ + b) * NFT + ft) * 2 + 0) * 36) * 2 * FT;
#pragma unroll
        for (int i = 0; i < 9; ++i) {
            int p = g * 9 + i;
            psdPart[base + (p * 2 + 0) * FT + fl] = aSr[i];
            psdPart[base + (p * 2 + 1) * FT + fl] = aSi[i];
            psdPart[base + (36 * 2 + p * 2 + 0) * FT + fl] = aNr[i];
            psdPart[base + (36 * 2 + p * 2 + 1) * FT + fl] = aNi[i];
        }
    }
    // ---- reduce mask_speech time-sum per f (speech threads are pairs 2f, 2f+1) ----
    sred[tid] = sS;
    __syncthreads();
    if (tid < 64) {
        float s = sred[tid * 2] + sred[tid * 2 + 1];
        if ((f0 + tid) < F_) ssPart[((sp * B_ + b) * NFT + ft) * FT + tid] = s;
    }
}

// ---------------- Kernel 2a: reduce partials + attention features ----------------
// grid (NFT, B), block 256 = 64 f-lanes x 4 pair-groups (coalesced on FT stride).
__global__ __launch_bounds__(256) void k2a_reduce(
    const float* __restrict__ psdPart, const float* __restrict__ ssPart,
    float* __restrict__ psdC, float* __restrict__ feat, int nsp)
{
    const int ft = blockIdx.x, b = blockIdx.y;
    const int tid = threadIdx.x;
    const int flq = tid & 63, q = tid >> 6;
    const int f = ft * FT + flq;
    __shared__ float pl[FT * 73];
    __shared__ float sl[FT];

    float acc[2][9][2];
#pragma unroll
    for (int s = 0; s < 2; ++s)
#pragma unroll
        for (int i = 0; i < 9; ++i)
#pragma unroll
            for (int ri = 0; ri < 2; ++ri) acc[s][i][ri] = 0.f;

    for (int sp = 0; sp < nsp; ++sp) {
        int base = ((((sp * B_ + b) * NFT + ft) * 2) * 36) * 2 * FT;
#pragma unroll
        for (int s = 0; s < 2; ++s)
#pragma unroll
            for (int i = 0; i < 9; ++i)
#pragma unroll
                for (int ri = 0; ri < 2; ++ri)
                    acc[s][i][ri] += psdPart[base + ((s * 36 + q * 9 + i) * 2 + ri) * FT + flq];
    }

    if (f < F_) {
        int bf = b * F_ + f;
#pragma unroll
        for (int s = 0; s < 2; ++s)
#pragma unroll
            for (int i = 0; i < 9; ++i)
#pragma unroll
                for (int ri = 0; ri < 2; ++ri)
                    psdC[((s * 36 + q * 9 + i) * 2 + ri) * BF_ + bf] = acc[s][i][ri];
    }
#pragma unroll
    for (int i = 0; i < 9; ++i) {
        pl[flq * 73 + (q * 9 + i) * 2 + 0] = acc[0][i][0];
        pl[flq * 73 + (q * 9 + i) * 2 + 1] = acc[0][i][1];
    }
    if (q == 0) {
        float S = 0.f;
        for (int sp = 0; sp < nsp; ++sp) S += ssPart[((sp * B_ + b) * NFT + ft) * FT + flq];
        sl[flq] = S;
    }
    __syncthreads();

    const int fl2 = tid & 63, c0 = tid >> 6;
    const int f2 = ft * FT + fl2;
    if (f2 < F_) {
        float inv = 1.f / (7.f * (sl[fl2] + 1e-15f));
#pragma unroll
        for (int h = 0; h < 2; ++h) {
            int c = c0 + h * 4;
            float sr = 0.f, si = 0.f;
            for (int e = 0; e < 8; ++e) {
                if (e == c) continue;
                int r = c < e ? c : e, cc = c < e ? e : c;
                int p = 8 * r - (r * (r - 1)) / 2 + (cc - r);
                float vr = pl[fl2 * 73 + p * 2], vi = pl[fl2 * 73 + p * 2 + 1];
                sr += vr; si += (e > c) ? vi : -vi;
            }
            feat[(b * C_ + c) * F_ + f2] = sqrtf(sr * sr + si * si) * inv;
        }
    }
}

// ---------------- Kernel 2b: attention MLP -> e[b,c] ----------------
// grid (B*C)=64 blocks, block 320; thread a owns attention dim a (1 dot of length F).
// W chunk staged transposed in LDS (stride 321 -> conflict-free both directions).
__global__ __launch_bounds__(320) void k2b_att(
    const float* __restrict__ feat, const float* __restrict__ W,
    const float* __restrict__ bp, const float* __restrict__ wg,
    const float* __restrict__ bg, float* __restrict__ eBuf)
{
    const int b = blockIdx.x >> 3, c = blockIdx.x & 7;
    const int tid = threadIdx.x;
    __shared__ float featL[576];
    __shared__ float Wt[64 * 321];
    __shared__ float red[5];

    for (int i = tid; i < 576; i += 320)
        featL[i] = (i < F_) ? feat[(b * C_ + c) * F_ + i] : 0.f;

    float dot = bp[tid];
    for (int f0 = 0; f0 < 576; f0 += 64) {
        __syncthreads();
        for (int li = tid; li < 320 * 64; li += 320) {
            int a = li >> 6, fo = li & 63;
            int f = f0 + fo;
            Wt[fo * 321 + a] = (f < F_) ? W[a * F_ + f] : 0.f;
        }
        __syncthreads();
#pragma unroll
        for (int fo = 0; fo < 64; ++fo)
            dot += featL[f0 + fo] * Wt[fo * 321 + tid];
    }
    float eacc = tanhf(dot) * wg[tid];
#pragma unroll
    for (int off = 32; off >= 1; off >>= 1) eacc += __shfl_xor(eacc, off);
    if ((tid & 63) == 0) red[tid >> 6] = eacc;
    __syncthreads();
    if (tid == 0)
        eBuf[blockIdx.x] = red[0] + red[1] + red[2] + red[3] + red[4] + bg[0];
}

// ---------------- Kernel 3: softmax(u) + MVDR solve -> conj(ws) ----------------
// grid ceil(4104/32), block 128. 4 lanes per 8x16 complex augmented system; the 4
// lanes of a system share one wave -> LDS ops are wave-ordered, barriers are belt
// and braces only. Raw (unnormalized) PSDs: solve+trace normalization cancels.
__global__ __launch_bounds__(128) void k3_solve(
    const float* __restrict__ psdC, const float* __restrict__ eBuf,
    float* __restrict__ wsB)
{
    const int tid = threadIdx.x;
    const int sl_ = tid >> 2;
    const int j = tid & 3;
    int sysg = blockIdx.x * 32 + sl_;
    bool wv = sysg < BF_;
    int sys = wv ? sysg : BF_ - 1;
    __shared__ float aug[32 * 257];
    __shared__ float uL[64];
    float* A = &aug[sl_ * 257];
#define AG(r,cl,ri) A[((((r)*16+(cl))<<1)+(ri))]

    // softmax over channels per batch (redundant per block, trivial cost)
    if (tid < 64) {
        int bb = tid >> 3, ci = tid & 7;
        float ev[8]; float m = -1e30f;
#pragma unroll
        for (int i = 0; i < 8; ++i) { ev[i] = eBuf[bb * 8 + i]; m = fmaxf(m, ev[i]); }
        float s = 0.f;
#pragma unroll
        for (int i = 0; i < 8; ++i) s += expf(2.f * (ev[i] - m));
        uL[tid] = expf(2.f * (ev[ci] - m)) / s;
    }

    // load [psd_n | psd_s] from 36-pair Hermitian storage
#pragma unroll
    for (int r = 0; r < 8; ++r) {
#pragma unroll
        for (int ci2 = 0; ci2 < 4; ++ci2) {
            int col = j + ci2 * 4;
            int s = (col < 8) ? 1 : 0;            // A = psd_n (s=1), B = psd_s (s=0)
            int c2 = (col < 8) ? col : col - 8;
            int rr = r < c2 ? r : c2, cc = r < c2 ? c2 : r;
            int p = 8 * rr - (rr * (rr - 1)) / 2 + (cc - rr);
            float re = psdC[((s * 36 + p) * 2 + 0) * BF_ + sys];
            float im = psdC[((s * 36 + p) * 2 + 1) * BF_ + sys];
            if (c2 < r) im = -im;
            AG(r, col, 0) = re; AG(r, col, 1) = im;
        }
    }
    __syncthreads();

    for (int k = 0; k < 8; ++k) {
        int rb = k; float bm = -1.f;
        for (int r = k; r < 8; ++r) {
            float m = fabsf(AG(r, k, 0)) + fabsf(AG(r, k, 1));
            if (m > bm) { bm = m; rb = r; }
        }
        if (rb != k) {
#pragma unroll
            for (int ci2 = 0; ci2 < 4; ++ci2) {
                int col = j + ci2 * 4;
                float t0_ = AG(k, col, 0), t1_ = AG(k, col, 1);
                AG(k, col, 0) = AG(rb, col, 0); AG(k, col, 1) = AG(rb, col, 1);
                AG(rb, col, 0) = t0_; AG(rb, col, 1) = t1_;
            }
        }
        __syncthreads();
        float dr = AG(k, k, 0), di = AG(k, k, 1);
        float dd = dr * dr + di * di;
        float pr = dr / dd, pi = -di / dd;
        for (int r = k + 1; r < 8; ++r) {
            float ar = AG(r, k, 0), ai = AG(r, k, 1);
            float fr = ar * pr - ai * pi, fi = ar * pi + ai * pr;
#pragma unroll
            for (int ci2 = 0; ci2 < 4; ++ci2) {
                int col = j + ci2 * 4;
                if (col > k) {
                    float xr_ = AG(k, col, 0), xi_ = AG(k, col, 1);
                    AG(r, col, 0) -= fr * xr_ - fi * xi_;
                    AG(r, col, 1) -= fr * xi_ + fi * xr_;
                }
            }
        }
        __syncthreads();
    }

    // back substitution: each lane owns B-columns {j+8, j+12} -> lane-local
#pragma unroll
    for (int bc2 = 0; bc2 < 2; ++bc2) {
        int bc = j + 8 + bc2 * 4;
        for (int k = 7; k >= 0; --k) {
            float vr = AG(k, bc, 0), vi = AG(k, bc, 1);
            for (int r = k + 1; r < 8; ++r) {
                float ar = AG(k, r, 0), ai = AG(k, r, 1);
                float xr_ = AG(r, bc, 0), xi_ = AG(r, bc, 1);
                vr -= ar * xr_ - ai * xi_;
                vi -= ar * xi_ + ai * xr_;
            }
            float dr = AG(k, k, 0), di = AG(k, k, 1);
            float dd = dr * dr + di * di;
            float pr = dr / dd, pi = -di / dd;
            float tr_ = vr * pr - vi * pi;
            float ti_ = vr * pi + vi * pr;
            AG(k, bc, 0) = tr_; AG(k, bc, 1) = ti_;
        }
    }
    __syncthreads();

    float trr = 1e-15f, tri = 0.f;
#pragma unroll
    for (int i = 0; i < 8; ++i) { trr += AG(i, 8 + i, 0); tri += AG(i, 8 + i, 1); }
    float tdd = trr * trr + tri * tri;
    int b = sys / F_;
#pragma unroll
    for (int e2 = 0; e2 < 2; ++e2) {
        int e = j + e2 * 4;
        float nr = 0.f, ni = 0.f;
        for (int cch = 0; cch < 8; ++cch) {
            float uu = uL[b * 8 + cch];
            nr += AG(e, 8 + cch, 0) * uu;
            ni += AG(e, 8 + cch, 1) * uu;
        }
        float wr = (nr * trr + ni * tri) / tdd;
        float wi = (ni * trr - nr * tri) / tdd;
        if (wv) {
            wsB[(e * 2 + 0) * BF_ + sysg] = wr;    // store conj(ws)
            wsB[(e * 2 + 1) * BF_ + sysg] = -wi;
        }
    }
#undef AG
}

// ---------------- Kernel 4: beamform + transpose to (B,T,F) ----------------
// grid (NFT, 25, B), block 256 = 64 f-lanes x 4 t-groups; 10 t per thread.
__global__ __launch_bounds__(256) void k4_beam(
    const float* __restrict__ dre, const float* __restrict__ dim_,
    const float* __restrict__ wsB, float* __restrict__ out)
{
    const int ft = blockIdx.x, tt = blockIdx.y, b = blockIdx.z;
    const int tid = threadIdx.x;
    const int fl = tid & 63, tg = tid >> 6;
    const int f = ft * FT + fl;
    if (f >= F_) return;
    const int bf = b * F_ + f;
    float cr[8], ci[8];
#pragma unroll
    for (int c = 0; c < 8; ++c) {
        cr[c] = wsB[(c * 2 + 0) * BF_ + bf];
        ci[c] = wsB[(c * 2 + 1) * BF_ + bf];
    }
#pragma unroll
    for (int k = 0; k < 10; ++k) {
        int t = tt * 40 + tg * 10 + k;
        size_t base = (size_t)(b * T_ + t) * (C_ * F_) + f;
        float aR = 0.f, aI = 0.f;
#pragma unroll
        for (int c = 0; c < 8; ++c) {
            float xr = dre[base + c * F_], xi = dim_[base + c * F_];
            aR += cr[c] * xr - ci[c] * xi;
            aI += cr[c] * xi + ci[c] * xr;
        }
        out[(size_t)(b * T_ + t) * F_ + f] = aR;
        out[(size_t)B_ * T_ * F_ + (size_t)(b * T_ + t) * F_ + f] = aI;
    }
}

extern "C" void kernel_launch(void* const* d_in, const int* in_sizes, int n_in,
                              void* d_out, int out_size, void* d_ws, size_t ws_size,
                              hipStream_t stream)
{
    const float* dre = (const float*)d_in[0];
    const float* dim_ = (const float*)d_in[1];
    const float* mss = (const float*)d_in[2];
    const float* msn = (const float*)d_in[3];
    const float* W  = (const float*)d_in[4];
    const float* bp = (const float*)d_in[5];
    const float* wg = (const float*)d_in[6];
    const float* bg = (const float*)d_in[7];
    float* out = (float*)d_out;
    float* w0 = (float*)d_ws;

    // T-split candidates keep TL divisible by 4 (float4 mask loads stay aligned).
    const size_t per_split = (size_t)B_ * NFT * (2 * 36 * 2 * FT) + (size_t)B_ * NFT * FT;
    const size_t fixed_floats = (size_t)(2 * 36 * 2 * BF_) + (B_ * C_ * F_) + 64 + (C_ * 2 * BF_);
    const int cands[4] = {10, 5, 2, 1};
    int nsp = 1;
    for (int ci = 0; ci < 4; ++ci) {
        size_t need = 4 * ((size_t)cands[ci] * per_split + fixed_floats);
        if (need <= ws_size) { nsp = cands[ci]; break; }
    }
    const int TL = T_ / nsp;

    const size_t psdPartSz = (size_t)nsp * B_ * NFT * 2 * 36 * 2 * FT;
    const size_t ssPartSz  = (size_t)nsp * B_ * NFT * FT;
    float* psdPart = w0;
    float* ssPart  = psdPart + psdPartSz;
    float* psdC    = ssPart + ssPartSz;
    float* feat    = psdC + (size_t)(2 * 36 * 2 * BF_);
    float* eB      = feat + (size_t)(B_ * C_ * F_);
    float* wsB     = eB + 64;

    k1_psd<<<dim3(NFT, nsp, B_), 256, 0, stream>>>(dre, dim_, mss, msn, psdPart, ssPart, TL);
    k2a_reduce<<<dim3(NFT, B_), 256, 0, stream>>>(psdPart, ssPart, psdC, feat, nsp);
    k2b_att<<<dim3(B_ * C_), 320, 0, stream>>>(feat, W, bp, wg, bg, eB);
    k3_solve<<<dim3((BF_ + 31) / 32), 128, 0, stream>>>(psdC, eB, wsB);
    k4_beam<<<dim3(NFT, T_ / 40, B_), 256, 0, stream>>>(dre, dim_, wsB, out);
}

// Round 4
// 844.029 us; speedup vs baseline: 1.0607x; 1.0607x over previous
//
#include <hip/hip_runtime.h>
#include <math.h>

#define B_ 8
#define T_ 1000
#define C_ 8
#define F_ 513
#define ATT_ 320
#define BF_ (B_*F_)          // 4104
#define FT 32                // k1/k2a freq tile
#define NFT 17               // ceil(513/32)
#define PSD_J 4608           // 2s * 36p * 2ri * 32fl floats per (sp,b,ft)

// ---------------- Kernel 1: masked PSD accumulation ----------------
// grid (NFT, nsp, B), block 256. FT=32 freqs/block for occupancy (LDS ~21KB, grid >=1360).
// psd[c,e] = sum_t w[t] x[c,t] conj(x[e,t]), w = mean_c mask (unnormalized; MVDR is
// scale-invariant, only the attention feature divides by S in k2a).
// 8 thread-groups = 4 pair-nonets x 2 mask-types; masks staged in 16-t float4 superchunks.
__global__ __launch_bounds__(256) void k1_psd(
    const float* __restrict__ dre, const float* __restrict__ dim_,
    const float* __restrict__ mss, const float* __restrict__ msn,
    float* __restrict__ psdPart, float* __restrict__ ssPart, int TL)
{
    const int ft = blockIdx.x, sp = blockIdx.y, b = blockIdx.z;
    const int tid = threadIdx.x;
    const int f0 = ft * FT;
    const int t0 = sp * TL;

    __shared__ float2 xs[8 * 8 * 32];     // [t8][c][fl], 16 KB
    __shared__ float  msh[2 * 16 * 32];   // [s][trow][fl], 4 KB
    __shared__ float  sred[128];

    // mask persona: quad=tid&3 (4 t each), mfl=(tid>>2)&31 (freq), sm=tid>>7 (mask type)
    const int quad = tid & 3, mfl = (tid >> 2) & 31, sm = tid >> 7;
    const bool mval = (f0 + mfl) < F_;
    const float* __restrict__ mbase =
        (sm ? msn : mss) + (size_t)((b * F_ + f0 + mfl) * C_) * T_ + t0;

    // data-staging / compute persona: fl=tid&31 (freq), g=tid>>5 (8 groups)
    const int fl = tid & 31, g = tid >> 5;
    const bool fval = (f0 + fl) < F_;
    const size_t dbase0 = (size_t)(b * T_ + t0) * (C_ * F_) + (size_t)g * F_ + f0 + fl;
    const int s_ = g & 1, nb = g >> 1;    // mask-type, pair-nonet

    float aR[9], aI[9];
#pragma unroll
    for (int i = 0; i < 9; ++i) { aR[i] = 0.f; aI[i] = 0.f; }
    float sS = 0.f;

    const int nsc = (TL + 15) >> 4;       // 16-t superchunks
    for (int sc = 0; sc < nsc; ++sc) {
        // ---- stage channel-mean masks for 16 t (full 64B lines, float4) ----
        {
            float4 a4 = make_float4(0.f, 0.f, 0.f, 0.f);
            int tq = sc * 16 + quad * 4;
            if (mval && tq < TL) {        // TL%4==0 -> tq<TL implies tq+3<TL
                const float* mp = mbase + tq;
#pragma unroll
                for (int c = 0; c < C_; ++c) {
                    float4 v = *(const float4*)&mp[c * T_];
                    a4.x += v.x; a4.y += v.y; a4.z += v.z; a4.w += v.w;
                }
            }
            int mrow = sm * 512 + (quad * 4) * 32 + mfl;
            msh[mrow]          = a4.x * 0.125f;
            msh[mrow + 32]     = a4.y * 0.125f;
            msh[mrow + 64]     = a4.z * 0.125f;
            msh[mrow + 96]     = a4.w * 0.125f;
            if (!sm) sS += (a4.x + a4.y + a4.z + a4.w) * 0.125f;
        }
#pragma unroll 1
        for (int h = 0; h < 2; ++h) {
            int tb = sc * 16 + h * 8;
            if (tb >= TL) break;
            // ---- stage data: thread handles c=g, t=0..7, lanes over 32 f ----
#pragma unroll
            for (int t = 0; t < 8; ++t) {
                int tc = tb + t;
                float vr = 0.f, vi = 0.f;
                if (fval && tc < TL) {
                    size_t ix = dbase0 + (size_t)tc * (C_ * F_);
                    vr = dre[ix]; vi = dim_[ix];
                }
                xs[(t * 8 + g) * 32 + fl] = make_float2(vr, vi);
            }
            __syncthreads();
            // ---- accumulate outer products (zero-filled tails contribute 0) ----
#pragma unroll
            for (int t = 0; t < 8; ++t) {
                float m = msh[s_ * 512 + (h * 8 + t) * 32 + fl];
                float xr[8], xi[8];
#pragma unroll
                for (int c = 0; c < 8; ++c) {
                    float2 v = xs[(t * 8 + c) * 32 + fl];
                    xr[c] = v.x; xi[c] = v.y;
                }
#define PAIR(i,c,e) { float pr = xr[c]*xr[e] + xi[c]*xi[e]; \
                      float pi = xi[c]*xr[e] - xr[c]*xi[e]; \
                      aR[i] += m*pr; aI[i] += m*pi; }
                if (nb == 0)      { PAIR(0,0,0) PAIR(1,0,1) PAIR(2,0,2) PAIR(3,0,3) PAIR(4,0,4) PAIR(5,0,5) PAIR(6,0,6) PAIR(7,0,7) PAIR(8,1,1) }
                else if (nb == 1) { PAIR(0,1,2) PAIR(1,1,3) PAIR(2,1,4) PAIR(3,1,5) PAIR(4,1,6) PAIR(5,1,7) PAIR(6,2,2) PAIR(7,2,3) PAIR(8,2,4) }
                else if (nb == 2) { PAIR(0,2,5) PAIR(1,2,6) PAIR(2,2,7) PAIR(3,3,3) PAIR(4,3,4) PAIR(5,3,5) PAIR(6,3,6) PAIR(7,3,7) PAIR(8,4,4) }
                else              { PAIR(0,4,5) PAIR(1,4,6) PAIR(2,4,7) PAIR(3,5,5) PAIR(4,5,6) PAIR(5,5,7) PAIR(6,6,6) PAIR(7,6,7) PAIR(8,7,7) }
#undef PAIR
            }
            __syncthreads();
        }
    }

    // ---- write partials: [ (sp*B+b)*NFT+ft ][ ((s*36+p)*2+ri)*32 + fl ] ----
    if (fval) {
        size_t base = (size_t)((sp * B_ + b) * NFT + ft) * PSD_J;
#pragma unroll
        for (int i = 0; i < 9; ++i) {
            int p = nb * 9 + i;
            psdPart[base + ((s_ * 36 + p) * 2 + 0) * 32 + fl] = aR[i];
            psdPart[base + ((s_ * 36 + p) * 2 + 1) * 32 + fl] = aI[i];
        }
    }
    // ---- speech-mask time sum per f (speech persona = tid<128, tid = f*4+quad) ----
    if (tid < 128) sred[tid] = sS;
    __syncthreads();
    if (tid < 32) {
        float s = sred[tid * 4] + sred[tid * 4 + 1] + sred[tid * 4 + 2] + sred[tid * 4 + 3];
        if ((f0 + tid) < F_) ssPart[((sp * B_ + b) * NFT + ft) * FT + tid] = s;
    }
}

// ---------------- Kernel 2a: reduce partials + attention features ----------------
// grid (NFT, B), block 256. Flat element-parallel sum over splits, then features.
__global__ __launch_bounds__(256) void k2a_reduce(
    const float* __restrict__ psdPart, const float* __restrict__ ssPart,
    float* __restrict__ psdC, float* __restrict__ feat, int nsp)
{
    const int ft = blockIdx.x, b = blockIdx.y;
    const int tid = threadIdx.x;
    const int f0 = ft * FT;
    __shared__ float pl[32 * 73];
    __shared__ float sl[32];

#pragma unroll 1
    for (int i = 0; i < PSD_J / 256; ++i) {
        int j = tid + 256 * i;
        float acc = 0.f;
        for (int sp = 0; sp < nsp; ++sp)
            acc += psdPart[(size_t)((sp * B_ + b) * NFT + ft) * PSD_J + j];
        int fl = j & 31;
        int mcode = j >> 5;            // (s*36+p)*2+ri
        int ri = mcode & 1;
        int spp = mcode >> 1;
        int s = (spp >= 36) ? 1 : 0;
        int p = spp - 36 * s;
        if ((f0 + fl) < F_)
            psdC[(size_t)mcode * BF_ + b * F_ + f0 + fl] = acc;
        if (s == 0) pl[fl * 73 + p * 2 + ri] = acc;
    }
    if (tid < 32) {
        float S = 0.f;
        for (int sp = 0; sp < nsp; ++sp)
            S += ssPart[((sp * B_ + b) * NFT + ft) * FT + tid];
        sl[tid] = S;
    }
    __syncthreads();

    const int fl2 = tid & 31, c = tid >> 5;   // 32 f x 8 c = 256 threads
    const int f2 = f0 + fl2;
    if (f2 < F_) {
        float inv = 1.f / (7.f * (sl[fl2] + 1e-15f));
        float sr = 0.f, si = 0.f;
#pragma unroll
        for (int e = 0; e < 8; ++e) {
            if (e == c) continue;
            int r = c < e ? c : e, cc = c < e ? e : c;
            int p = 8 * r - (r * (r - 1)) / 2 + (cc - r);
            float vr = pl[fl2 * 73 + p * 2], vi = pl[fl2 * 73 + p * 2 + 1];
            sr += vr; si += (e > c) ? vi : -vi;
        }
        feat[(b * C_ + c) * F_ + f2] = sqrtf(sr * sr + si * si) * inv;
    }
}

// ---------------- Kernel 2b: attention MLP partials ----------------
// grid (B, C, 5): each block does a 64-wide a-tile; 16.6KB LDS transposed W tile.
// ePart[(b*C+c)*5+at] = sum_a tanh(feat . W[a] + bp[a]) * wg[a] over the tile.
__global__ __launch_bounds__(256) void k2b_att(
    const float* __restrict__ feat, const float* __restrict__ W,
    const float* __restrict__ bp, const float* __restrict__ wg,
    float* __restrict__ ePart)
{
    const int b = blockIdx.x, c = blockIdx.y, at = blockIdx.z;
    const int a0 = at * 64;
    const int tid = threadIdx.x;
    __shared__ float featL[576];
    __shared__ float Wt[64 * 65];
    __shared__ float dsum[4][64];

    for (int i = tid; i < 576; i += 256)
        featL[i] = (i < F_) ? feat[(b * C_ + c) * F_ + i] : 0.f;

    const int al = tid & 63, q = tid >> 6;
    float partial = 0.f;
    for (int fc = 0; fc < F_; fc += 64) {
        __syncthreads();
#pragma unroll
        for (int i = 0; i < 16; ++i) {        // stage Wt[fo][a], coalesced over fo
            int item = tid + 256 * i;
            int fo = item & 63, a = item >> 6;
            int f = fc + fo;
            Wt[fo * 65 + a] = (f < F_) ? W[(size_t)(a0 + a) * F_ + f] : 0.f;
        }
        __syncthreads();
#pragma unroll
        for (int k = 0; k < 16; ++k) {
            int fo = q * 16 + k;
            partial += featL[fc + fo] * Wt[fo * 65 + al];
        }
    }
    dsum[q][al] = partial;
    __syncthreads();
    if (tid < 64) {
        float dot = dsum[0][tid] + dsum[1][tid] + dsum[2][tid] + dsum[3][tid] + bp[a0 + tid];
        float ep = tanhf(dot) * wg[a0 + tid];
#pragma unroll
        for (int off = 32; off >= 1; off >>= 1) ep += __shfl_xor(ep, off);
        if (tid == 0) ePart[(b * C_ + c) * 5 + at] = ep;
    }
}

// ---------------- Kernel 3: e-reduce + softmax(u) + MVDR solve -> conj(ws) ----------------
// grid ceil(4104/32), block 128. 4 lanes per 8x16 complex augmented system.
__global__ __launch_bounds__(128) void k3_solve(
    const float* __restrict__ psdC, const float* __restrict__ ePart,
    const float* __restrict__ bg, float* __restrict__ wsB)
{
    const int tid = threadIdx.x;
    const int sl_ = tid >> 2;
    const int j = tid & 3;
    int sysg = blockIdx.x * 32 + sl_;
    bool wv = sysg < BF_;
    int sys = wv ? sysg : BF_ - 1;
    __shared__ float aug[32 * 257];
    __shared__ float eL[64];
    __shared__ float uL[64];
    float* A = &aug[sl_ * 257];
#define AG(r,cl,ri) A[((((r)*16+(cl))<<1)+(ri))]

    if (tid < 64) {
        float e = bg[0];
#pragma unroll
        for (int z = 0; z < 5; ++z) e += ePart[tid * 5 + z];
        eL[tid] = e;
    }

    // load [psd_n | psd_s] from 36-pair Hermitian storage
#pragma unroll
    for (int r = 0; r < 8; ++r) {
#pragma unroll
        for (int ci2 = 0; ci2 < 4; ++ci2) {
            int col = j + ci2 * 4;
            int s = (col < 8) ? 1 : 0;            // A = psd_n (s=1), B = psd_s (s=0)
            int c2 = (col < 8) ? col : col - 8;
            int rr = r < c2 ? r : c2, cc = r < c2 ? c2 : r;
            int p = 8 * rr - (rr * (rr - 1)) / 2 + (cc - rr);
            float re = psdC[(size_t)((s * 36 + p) * 2 + 0) * BF_ + sys];
            float im = psdC[(size_t)((s * 36 + p) * 2 + 1) * BF_ + sys];
            if (c2 < r) im = -im;
            AG(r, col, 0) = re; AG(r, col, 1) = im;
        }
    }
    __syncthreads();

    // softmax (uses eL; uL read only after later barriers)
    if (tid < 64) {
        int bb = tid >> 3;
        float m = -1e30f;
#pragma unroll
        for (int i = 0; i < 8; ++i) m = fmaxf(m, eL[bb * 8 + i]);
        float s = 0.f;
#pragma unroll
        for (int i = 0; i < 8; ++i) s += expf(2.f * (eL[bb * 8 + i] - m));
        uL[tid] = expf(2.f * (eL[tid] - m)) / s;
    }

    for (int k = 0; k < 8; ++k) {
        int rb = k; float bm = -1.f;
        for (int r = k; r < 8; ++r) {
            float m = fabsf(AG(r, k, 0)) + fabsf(AG(r, k, 1));
            if (m > bm) { bm = m; rb = r; }
        }
        if (rb != k) {
#pragma unroll
            for (int ci2 = 0; ci2 < 4; ++ci2) {
                int col = j + ci2 * 4;
                float t0_ = AG(k, col, 0), t1_ = AG(k, col, 1);
                AG(k, col, 0) = AG(rb, col, 0); AG(k, col, 1) = AG(rb, col, 1);
                AG(rb, col, 0) = t0_; AG(rb, col, 1) = t1_;
            }
        }
        __syncthreads();
        float dr = AG(k, k, 0), di = AG(k, k, 1);
        float dd = dr * dr + di * di;
        float pr = dr / dd, pi = -di / dd;
        for (int r = k + 1; r < 8; ++r) {
            float ar = AG(r, k, 0), ai = AG(r, k, 1);
            float fr = ar * pr - ai * pi, fi = ar * pi + ai * pr;
#pragma unroll
            for (int ci2 = 0; ci2 < 4; ++ci2) {
                int col = j + ci2 * 4;
                if (col > k) {
                    float xr_ = AG(k, col, 0), xi_ = AG(k, col, 1);
                    AG(r, col, 0) -= fr * xr_ - fi * xi_;
                    AG(r, col, 1) -= fr * xi_ + fi * xr_;
                }
            }
        }
        __syncthreads();
    }

    // back substitution: each lane owns B-columns {j+8, j+12}
#pragma unroll
    for (int bc2 = 0; bc2 < 2; ++bc2) {
        int bc = j + 8 + bc2 * 4;
        for (int k = 7; k >= 0; --k) {
            float vr = AG(k, bc, 0), vi = AG(k, bc, 1);
            for (int r = k + 1; r < 8; ++r) {
                float ar = AG(k, r, 0), ai = AG(k, r, 1);
                float xr_ = AG(r, bc, 0), xi_ = AG(r, bc, 1);
                vr -= ar * xr_ - ai * xi_;
                vi -= ar * xi_ + ai * xr_;
            }
            float dr = AG(k, k, 0), di = AG(k, k, 1);
            float dd = dr * dr + di * di;
            float pr = dr / dd, pi = -di / dd;
            float tr_ = vr * pr - vi * pi;
            float ti_ = vr * pi + vi * pr;
            AG(k, bc, 0) = tr_; AG(k, bc, 1) = ti_;
        }
    }
    __syncthreads();

    float trr = 1e-15f, tri = 0.f;
#pragma unroll
    for (int i = 0; i < 8; ++i) { trr += AG(i, 8 + i, 0); tri += AG(i, 8 + i, 1); }
    float tdd = trr * trr + tri * tri;
    int b = sys / F_;
#pragma unroll
    for (int e2 = 0; e2 < 2; ++e2) {
        int e = j + e2 * 4;
        float nr = 0.f, ni = 0.f;
#pragma unroll
        for (int cch = 0; cch < 8; ++cch) {
            float uu = uL[b * 8 + cch];
            nr += AG(e, 8 + cch, 0) * uu;
            ni += AG(e, 8 + cch, 1) * uu;
        }
        float wr = (nr * trr + ni * tri) / tdd;
        float wi = (ni * trr - nr * tri) / tdd;
        if (wv) {
            wsB[(e * 2 + 0) * BF_ + sysg] = wr;    // store conj(ws)
            wsB[(e * 2 + 1) * BF_ + sysg] = -wi;
        }
    }
#undef AG
}

// ---------------- Kernel 4: beamform + transpose to (B,T,F) ----------------
// grid (9, 25, B), block 256 = 64 f-lanes x 4 t-groups; 10 t per thread.
__global__ __launch_bounds__(256) void k4_beam(
    const float* __restrict__ dre, const float* __restrict__ dim_,
    const float* __restrict__ wsB, float* __restrict__ out)
{
    const int ft = blockIdx.x, tt = blockIdx.y, b = blockIdx.z;
    const int tid = threadIdx.x;
    const int fl = tid & 63, tg = tid >> 6;
    const int f = ft * 64 + fl;
    if (f >= F_) return;
    const int bf = b * F_ + f;
    float cr[8], ci[8];
#pragma unroll
    for (int c = 0; c < 8; ++c) {
        cr[c] = wsB[(c * 2 + 0) * BF_ + bf];
        ci[c] = wsB[(c * 2 + 1) * BF_ + bf];
    }
#pragma unroll
    for (int k = 0; k < 10; ++k) {
        int t = tt * 40 + tg * 10 + k;
        size_t base = (size_t)(b * T_ + t) * (C_ * F_) + f;
        float aR = 0.f, aI = 0.f;
#pragma unroll
        for (int c = 0; c < 8; ++c) {
            float xr = dre[base + c * F_], xi = dim_[base + c * F_];
            aR += cr[c] * xr - ci[c] * xi;
            aI += cr[c] * xi + ci[c] * xr;
        }
        out[(size_t)(b * T_ + t) * F_ + f] = aR;
        out[(size_t)B_ * T_ * F_ + (size_t)(b * T_ + t) * F_ + f] = aI;
    }
}

extern "C" void kernel_launch(void* const* d_in, const int* in_sizes, int n_in,
                              void* d_out, int out_size, void* d_ws, size_t ws_size,
                              hipStream_t stream)
{
    const float* dre = (const float*)d_in[0];
    const float* dim_ = (const float*)d_in[1];
    const float* mss = (const float*)d_in[2];
    const float* msn = (const float*)d_in[3];
    const float* W  = (const float*)d_in[4];
    const float* bp = (const float*)d_in[5];
    const float* wg = (const float*)d_in[6];
    const float* bg = (const float*)d_in[7];
    float* out = (float*)d_out;
    float* w0 = (float*)d_ws;

    // ws ladder: TL must stay divisible by 4 (float4 mask loads).
    const size_t per_split = (size_t)NFT * B_ * PSD_J + (size_t)NFT * B_ * FT;
    const size_t fixed_floats = (size_t)(2 * 36 * 2) * BF_   // psdC
                              + (size_t)B_ * C_ * F_          // feat
                              + 320                           // ePart
                              + (size_t)C_ * 2 * BF_;         // wsB
    const int cands[5] = {25, 10, 5, 2, 1};
    int nsp = 1;
    for (int ci = 0; ci < 5; ++ci) {
        size_t need = 4 * ((size_t)cands[ci] * per_split + fixed_floats);
        if (need <= ws_size) { nsp = cands[ci]; break; }
    }
    const int TL = T_ / nsp;

    float* psdPart = w0;
    float* ssPart  = psdPart + (size_t)nsp * NFT * B_ * PSD_J;
    float* psdC    = ssPart + (size_t)nsp * NFT * B_ * FT;
    float* feat    = psdC + (size_t)(2 * 36 * 2) * BF_;
    float* eP      = feat + (size_t)B_ * C_ * F_;
    float* wsB     = eP + 320;

    k1_psd<<<dim3(NFT, nsp, B_), 256, 0, stream>>>(dre, dim_, mss, msn, psdPart, ssPart, TL);
    k2a_reduce<<<dim3(NFT, B_), 256, 0, stream>>>(psdPart, ssPart, psdC, feat, nsp);
    k2b_att<<<dim3(B_, C_, 5), 256, 0, stream>>>(feat, W, bp, wg, eP);
    k3_solve<<<dim3((BF_ + 31) / 32), 128, 0, stream>>>(psdC, eP, bg, wsB);
    k4_beam<<<dim3(9, T_ / 40, B_), 256, 0, stream>>>(dre, dim_, wsB, out);
}

// Round 5
// 741.123 us; speedup vs baseline: 1.2080x; 1.1389x over previous
//
#include <hip/hip_runtime.h>
#include <math.h>

#define B_ 8
#define T_ 1000
#define C_ 8
#define F_ 513
#define ATT_ 320
#define BF_ (B_*F_)          // 4104
#define FT 32                // k1b/k2a freq tile
#define NFT 17               // ceil(513/32)
#define PSD_J 4608           // 2s * 36p * 2ri * 32fl floats per (sp,b,ft)
#define TPAD 576             // mw row stride (covers 9 f-tiles of 64, 64B-aligned)

// ---------------- Kernel 0: mask channel-mean + transpose ----------------
// grid (9 ftile, 8 ttile, 16 = s*8+b), block 256.
// Reads mask[b,f,c,t] (t-contiguous float4), mean over c, writes mw[s][b][t][f]
// (f-contiguous rows, TPAD=576 stride -> 64B-aligned coalesced 256B stores).
// Speech blocks also emit per-(b,ttile,f) t-sums for the feature normalizer.
__global__ __launch_bounds__(256) void k0_mask(
    const float* __restrict__ mss, const float* __restrict__ msn,
    float* __restrict__ mw, float* __restrict__ ssp)
{
    const int ftile = blockIdx.x, tt = blockIdx.y, z = blockIdx.z;
    const int s = z >> 3, b = z & 7;
    const float* __restrict__ src = s ? msn : mss;
    const int f0 = ftile * 64, t0 = tt * 128;
    const int tid = threadIdx.x;

    __shared__ float lt[128 * 66];   // [t_local][fa], stride 66 kills write conflicts
    __shared__ float red[256];

    // read persona: fa = freq-in-tile (0..63), tq = t-interleave (0..3)
    const int fa = tid >> 2, tq = tid & 3;
    float4 a[8];
#pragma unroll
    for (int k = 0; k < 8; ++k) a[k] = make_float4(0.f, 0.f, 0.f, 0.f);

    if ((f0 + fa) < F_) {
        const float* __restrict__ mp = src + (size_t)((b * F_ + f0 + fa) * C_) * T_;
#pragma unroll
        for (int c = 0; c < C_; ++c) {
#pragma unroll
            for (int k = 0; k < 8; ++k) {
                int tb = t0 + tq * 4 + k * 16;   // mult of 4; T_%4==0 -> chunk fully valid
                if (tb < T_) {
                    float4 v = *(const float4*)&mp[(size_t)c * T_ + tb];
                    a[k].x += v.x; a[k].y += v.y; a[k].z += v.z; a[k].w += v.w;
                }
            }
        }
    }
#pragma unroll
    for (int k = 0; k < 8; ++k) {
        int tl0 = tq * 4 + k * 16;
        lt[(tl0 + 0) * 66 + fa] = a[k].x * 0.125f;
        lt[(tl0 + 1) * 66 + fa] = a[k].y * 0.125f;
        lt[(tl0 + 2) * 66 + fa] = a[k].z * 0.125f;
        lt[(tl0 + 3) * 66 + fa] = a[k].w * 0.125f;
    }
    __syncthreads();

    // write persona: fw = freq lane (0..63), tr = t-quarter (0..3)
    const int fw = tid & 63, tr = tid >> 6;
    float sum = 0.f;
#pragma unroll 4
    for (int tt2 = 0; tt2 < 32; ++tt2) {
        int tl_ = tr * 32 + tt2;
        float v = lt[tl_ * 66 + fw];
        sum += v;
        int tg_ = t0 + tl_;
        if (tg_ < T_)
            mw[((size_t)(s * B_ + b) * T_ + tg_) * TPAD + f0 + fw] = v;
    }
    if (s == 0) {
        red[tid] = sum;
        __syncthreads();
        if (tid < 64)
            ssp[(b * 8 + tt) * TPAD + f0 + tid] =
                red[tid] + red[64 + tid] + red[128 + tid] + red[192 + tid];
    }
}

// ---------------- Kernel 1b: PSD accumulation (no LDS, no barriers) ----------------
// grid (NFT, nsp, B), block 128 = 32 f-lanes x 4 pair-nonets. Each thread owns
// 9 Hermitian pairs x {speech,noise} in registers; all loads lanes-over-f coalesced.
__global__ __launch_bounds__(128, 4) void k1b_psd(
    const float* __restrict__ dre, const float* __restrict__ dim_,
    const float* __restrict__ mw, float* __restrict__ psdPart, int TL)
{
    const int ft = blockIdx.x, sp = blockIdx.y, b = blockIdx.z;
    const int tid = threadIdx.x;
    const int fl = tid & 31, nb = tid >> 5;
    const int f0 = ft * FT;
    const int t0 = sp * TL;
    const bool fval = (f0 + fl) < F_;

    const float* __restrict__ mwS = mw + ((size_t)b * T_ + t0) * TPAD + f0 + fl;
    const float* __restrict__ mwN = mw + ((size_t)(B_ + b) * T_ + t0) * TPAD + f0 + fl;
    const size_t dbase = (size_t)(b * T_ + t0) * (C_ * F_) + f0 + fl;

    float aSr[9], aSi[9], aNr[9], aNi[9];
#pragma unroll
    for (int i = 0; i < 9; ++i) { aSr[i]=0.f; aSi[i]=0.f; aNr[i]=0.f; aNi[i]=0.f; }

#pragma unroll 2
    for (int t = 0; t < TL; ++t) {
        float m_s = mwS[(size_t)t * TPAD];
        float m_n = mwN[(size_t)t * TPAD];
        float xr[8], xi[8];
        if (fval) {
            size_t ix = dbase + (size_t)t * (C_ * F_);
#pragma unroll
            for (int c = 0; c < 8; ++c) { xr[c] = dre[ix + c * F_]; xi[c] = dim_[ix + c * F_]; }
        } else {
#pragma unroll
            for (int c = 0; c < 8; ++c) { xr[c] = 0.f; xi[c] = 0.f; }
        }
#define PAIR(i,c,e) { float pr = xr[c]*xr[e] + xi[c]*xi[e]; \
                      float pi = xi[c]*xr[e] - xr[c]*xi[e]; \
                      aSr[i] += m_s*pr; aSi[i] += m_s*pi;   \
                      aNr[i] += m_n*pr; aNi[i] += m_n*pi; }
        if (nb == 0)      { PAIR(0,0,0) PAIR(1,0,1) PAIR(2,0,2) PAIR(3,0,3) PAIR(4,0,4) PAIR(5,0,5) PAIR(6,0,6) PAIR(7,0,7) PAIR(8,1,1) }
        else if (nb == 1) { PAIR(0,1,2) PAIR(1,1,3) PAIR(2,1,4) PAIR(3,1,5) PAIR(4,1,6) PAIR(5,1,7) PAIR(6,2,2) PAIR(7,2,3) PAIR(8,2,4) }
        else if (nb == 2) { PAIR(0,2,5) PAIR(1,2,6) PAIR(2,2,7) PAIR(3,3,3) PAIR(4,3,4) PAIR(5,3,5) PAIR(6,3,6) PAIR(7,3,7) PAIR(8,4,4) }
        else              { PAIR(0,4,5) PAIR(1,4,6) PAIR(2,4,7) PAIR(3,5,5) PAIR(4,5,6) PAIR(5,5,7) PAIR(6,6,6) PAIR(7,6,7) PAIR(8,7,7) }
#undef PAIR
    }

    if (fval) {
        size_t base = (size_t)((sp * B_ + b) * NFT + ft) * PSD_J;
#pragma unroll
        for (int i = 0; i < 9; ++i) {
            int p = nb * 9 + i;
            psdPart[base + ((0 * 36 + p) * 2 + 0) * 32 + fl] = aSr[i];
            psdPart[base + ((0 * 36 + p) * 2 + 1) * 32 + fl] = aSi[i];
            psdPart[base + ((1 * 36 + p) * 2 + 0) * 32 + fl] = aNr[i];
            psdPart[base + ((1 * 36 + p) * 2 + 1) * 32 + fl] = aNi[i];
        }
    }
}

// ---------------- Kernel 2a: flat partial reduction ----------------
// grid (NFT, B, 18) blocks x 256 thr: one element of PSD_J per thread.
__global__ __launch_bounds__(256) void k2a_sum(
    const float* __restrict__ psdPart, float* __restrict__ psdC, int nsp)
{
    const int ft = blockIdx.x, b = blockIdx.y, ch = blockIdx.z;
    const int j = ch * 256 + threadIdx.x;
    const int fl = j & 31, mcode = j >> 5;
    float acc = 0.f;
    for (int sp = 0; sp < nsp; ++sp)
        acc += psdPart[(size_t)((sp * B_ + b) * NFT + ft) * PSD_J + j];
    if ((ft * FT + fl) < F_)
        psdC[(size_t)mcode * BF_ + b * F_ + ft * FT + fl] = acc;
}

// ---------------- Kernel 2f: attention features ----------------
// grid (NFT, B), block 256 = 32 f x 8 c.
__global__ __launch_bounds__(256) void k2f_feat(
    const float* __restrict__ psdC, const float* __restrict__ ssp,
    float* __restrict__ feat)
{
    const int ft = blockIdx.x, b = blockIdx.y;
    const int tid = threadIdx.x;
    const int f0 = ft * FT;
    __shared__ float pl[32 * 73];
    __shared__ float sl[32];

    for (int idx = tid; idx < 32 * 72; idx += 256) {
        int fl = idx & 31, mc = idx >> 5;          // mc = p*2+ri (speech block)
        float v = 0.f;
        if ((f0 + fl) < F_) v = psdC[(size_t)mc * BF_ + b * F_ + f0 + fl];
        pl[fl * 73 + mc] = v;
    }
    if (tid < 32) {
        float S = 0.f;
#pragma unroll
        for (int tt = 0; tt < 8; ++tt) S += ssp[(b * 8 + tt) * TPAD + f0 + tid];
        sl[tid] = S;
    }
    __syncthreads();

    const int fl2 = tid & 31, c = tid >> 5;
    const int f2 = f0 + fl2;
    if (f2 < F_) {
        float inv = 1.f / (7.f * (sl[fl2] + 1e-15f));
        float sr = 0.f, si = 0.f;
#pragma unroll
        for (int e = 0; e < 8; ++e) {
            if (e == c) continue;
            int r = c < e ? c : e, cc = c < e ? e : c;
            int p = 8 * r - (r * (r - 1)) / 2 + (cc - r);
            float vr = pl[fl2 * 73 + p * 2], vi = pl[fl2 * 73 + p * 2 + 1];
            sr += vr; si += (e > c) ? vi : -vi;
        }
        feat[(b * C_ + c) * F_ + f2] = sqrtf(sr * sr + si * si) * inv;
    }
}

// ---------------- Kernel 2b: attention MLP partials ----------------
// grid (B, C, 5): 64-wide a-tile per block; transposed W tile in LDS.
__global__ __launch_bounds__(256) void k2b_att(
    const float* __restrict__ feat, const float* __restrict__ W,
    const float* __restrict__ bp, const float* __restrict__ wg,
    float* __restrict__ ePart)
{
    const int b = blockIdx.x, c = blockIdx.y, at = blockIdx.z;
    const int a0 = at * 64;
    const int tid = threadIdx.x;
    __shared__ float featL[576];
    __shared__ float Wt[64 * 65];
    __shared__ float dsum[4][64];

    for (int i = tid; i < 576; i += 256)
        featL[i] = (i < F_) ? feat[(b * C_ + c) * F_ + i] : 0.f;

    const int al = tid & 63, q = tid >> 6;
    float partial = 0.f;
    for (int fc = 0; fc < F_; fc += 64) {
        __syncthreads();
#pragma unroll
        for (int i = 0; i < 16; ++i) {
            int item = tid + 256 * i;
            int fo = item & 63, a = item >> 6;
            int f = fc + fo;
            Wt[fo * 65 + a] = (f < F_) ? W[(size_t)(a0 + a) * F_ + f] : 0.f;
        }
        __syncthreads();
#pragma unroll
        for (int k = 0; k < 16; ++k) {
            int fo = q * 16 + k;
            partial += featL[fc + fo] * Wt[fo * 65 + al];
        }
    }
    dsum[q][al] = partial;
    __syncthreads();
    if (tid < 64) {
        float dot = dsum[0][tid] + dsum[1][tid] + dsum[2][tid] + dsum[3][tid] + bp[a0 + tid];
        float ep = tanhf(dot) * wg[a0 + tid];
#pragma unroll
        for (int off = 32; off >= 1; off >>= 1) ep += __shfl_xor(ep, off);
        if (tid == 0) ePart[(b * C_ + c) * 5 + at] = ep;
    }
}

// ---------------- Kernel 3: e-reduce + softmax(u) + MVDR solve -> conj(ws) ----------------
__global__ __launch_bounds__(128) void k3_solve(
    const float* __restrict__ psdC, const float* __restrict__ ePart,
    const float* __restrict__ bg, float* __restrict__ wsB)
{
    const int tid = threadIdx.x;
    const int sl_ = tid >> 2;
    const int j = tid & 3;
    int sysg = blockIdx.x * 32 + sl_;
    bool wv = sysg < BF_;
    int sys = wv ? sysg : BF_ - 1;
    __shared__ float aug[32 * 257];
    __shared__ float eL[64];
    __shared__ float uL[64];
    float* A = &aug[sl_ * 257];
#define AG(r,cl,ri) A[((((r)*16+(cl))<<1)+(ri))]

    if (tid < 64) {
        float e = bg[0];
#pragma unroll
        for (int z = 0; z < 5; ++z) e += ePart[tid * 5 + z];
        eL[tid] = e;
    }

#pragma unroll
    for (int r = 0; r < 8; ++r) {
#pragma unroll
        for (int ci2 = 0; ci2 < 4; ++ci2) {
            int col = j + ci2 * 4;
            int s = (col < 8) ? 1 : 0;            // A = psd_n, B = psd_s
            int c2 = (col < 8) ? col : col - 8;
            int rr = r < c2 ? r : c2, cc = r < c2 ? c2 : r;
            int p = 8 * rr - (rr * (rr - 1)) / 2 + (cc - rr);
            float re = psdC[(size_t)((s * 36 + p) * 2 + 0) * BF_ + sys];
            float im = psdC[(size_t)((s * 36 + p) * 2 + 1) * BF_ + sys];
            if (c2 < r) im = -im;
            AG(r, col, 0) = re; AG(r, col, 1) = im;
        }
    }
    __syncthreads();

    if (tid < 64) {
        int bb = tid >> 3;
        float m = -1e30f;
#pragma unroll
        for (int i = 0; i < 8; ++i) m = fmaxf(m, eL[bb * 8 + i]);
        float s = 0.f;
#pragma unroll
        for (int i = 0; i < 8; ++i) s += expf(2.f * (eL[bb * 8 + i] - m));
        uL[tid] = expf(2.f * (eL[tid] - m)) / s;
    }

    for (int k = 0; k < 8; ++k) {
        int rb = k; float bm = -1.f;
        for (int r = k; r < 8; ++r) {
            float m = fabsf(AG(r, k, 0)) + fabsf(AG(r, k, 1));
            if (m > bm) { bm = m; rb = r; }
        }
        if (rb != k) {
#pragma unroll
            for (int ci2 = 0; ci2 < 4; ++ci2) {
                int col = j + ci2 * 4;
                float t0_ = AG(k, col, 0), t1_ = AG(k, col, 1);
                AG(k, col, 0) = AG(rb, col, 0); AG(k, col, 1) = AG(rb, col, 1);
                AG(rb, col, 0) = t0_; AG(rb, col, 1) = t1_;
            }
        }
        __syncthreads();
        float dr = AG(k, k, 0), di = AG(k, k, 1);
        float dd = dr * dr + di * di;
        float pr = dr / dd, pi = -di / dd;
        for (int r = k + 1; r < 8; ++r) {
            float ar = AG(r, k, 0), ai = AG(r, k, 1);
            float fr = ar * pr - ai * pi, fi = ar * pi + ai * pr;
#pragma unroll
            for (int ci2 = 0; ci2 < 4; ++ci2) {
                int col = j + ci2 * 4;
                if (col > k) {
                    float xr_ = AG(k, col, 0), xi_ = AG(k, col, 1);
                    AG(r, col, 0) -= fr * xr_ - fi * xi_;
                    AG(r, col, 1) -= fr * xi_ + fi * xr_;
                }
            }
        }
        __syncthreads();
    }

#pragma unroll
    for (int bc2 = 0; bc2 < 2; ++bc2) {
        int bc = j + 8 + bc2 * 4;
        for (int k = 7; k >= 0; --k) {
            float vr = AG(k, bc, 0), vi = AG(k, bc, 1);
            for (int r = k + 1; r < 8; ++r) {
                float ar = AG(k, r, 0), ai = AG(k, r, 1);
                float xr_ = AG(r, bc, 0), xi_ = AG(r, bc, 1);
                vr -= ar * xr_ - ai * xi_;
                vi -= ar * xi_ + ai * xr_;
            }
            float dr = AG(k, k, 0), di = AG(k, k, 1);
            float dd = dr * dr + di * di;
            float pr = dr / dd, pi = -di / dd;
            float tr_ = vr * pr - vi * pi;
            float ti_ = vr * pi + vi * pr;
            AG(k, bc, 0) = tr_; AG(k, bc, 1) = ti_;
        }
    }
    __syncthreads();

    float trr = 1e-15f, tri = 0.f;
#pragma unroll
    for (int i = 0; i < 8; ++i) { trr += AG(i, 8 + i, 0); tri += AG(i, 8 + i, 1); }
    float tdd = trr * trr + tri * tri;
    int b = sys / F_;
#pragma unroll
    for (int e2 = 0; e2 < 2; ++e2) {
        int e = j + e2 * 4;
        float nr = 0.f, ni = 0.f;
#pragma unroll
        for (int cch = 0; cch < 8; ++cch) {
            float uu = uL[b * 8 + cch];
            nr += AG(e, 8 + cch, 0) * uu;
            ni += AG(e, 8 + cch, 1) * uu;
        }
        float wr = (nr * trr + ni * tri) / tdd;
        float wi = (ni * trr - nr * tri) / tdd;
        if (wv) {
            wsB[(e * 2 + 0) * BF_ + sysg] = wr;    // store conj(ws)
            wsB[(e * 2 + 1) * BF_ + sysg] = -wi;
        }
    }
#undef AG
}

// ---------------- Kernel 4: beamform + transpose to (B,T,F) ----------------
// grid (9, 50, B), block 256 = 64 f-lanes x 4 t-groups; 5 t per thread.
__global__ __launch_bounds__(256) void k4_beam(
    const float* __restrict__ dre, const float* __restrict__ dim_,
    const float* __restrict__ wsB, float* __restrict__ out)
{
    const int ft = blockIdx.x, tt = blockIdx.y, b = blockIdx.z;
    const int tid = threadIdx.x;
    const int fl = tid & 63, tg = tid >> 6;
    const int f = ft * 64 + fl;
    if (f >= F_) return;
    const int bf = b * F_ + f;
    float cr[8], ci[8];
#pragma unroll
    for (int c = 0; c < 8; ++c) {
        cr[c] = wsB[(c * 2 + 0) * BF_ + bf];
        ci[c] = wsB[(c * 2 + 1) * BF_ + bf];
    }
#pragma unroll
    for (int k = 0; k < 5; ++k) {
        int t = tt * 20 + tg * 5 + k;
        size_t base = (size_t)(b * T_ + t) * (C_ * F_) + f;
        float aR = 0.f, aI = 0.f;
#pragma unroll
        for (int c = 0; c < 8; ++c) {
            float xr = dre[base + c * F_], xi = dim_[base + c * F_];
            aR += cr[c] * xr - ci[c] * xi;
            aI += cr[c] * xi + ci[c] * xr;
        }
        out[(size_t)(b * T_ + t) * F_ + f] = aR;
        out[(size_t)B_ * T_ * F_ + (size_t)(b * T_ + t) * F_ + f] = aI;
    }
}

extern "C" void kernel_launch(void* const* d_in, const int* in_sizes, int n_in,
                              void* d_out, int out_size, void* d_ws, size_t ws_size,
                              hipStream_t stream)
{
    const float* dre = (const float*)d_in[0];
    const float* dim_ = (const float*)d_in[1];
    const float* mss = (const float*)d_in[2];
    const float* msn = (const float*)d_in[3];
    const float* W  = (const float*)d_in[4];
    const float* bp = (const float*)d_in[5];
    const float* wg = (const float*)d_in[6];
    const float* bg = (const float*)d_in[7];
    float* out = (float*)d_out;
    float* w0 = (float*)d_ws;

    const size_t mwSz   = (size_t)2 * B_ * T_ * TPAD;     // 9.216M floats
    const size_t sspSz  = (size_t)B_ * 8 * TPAD;
    const size_t psdCSz = (size_t)144 * BF_;
    const size_t featSz = (size_t)B_ * C_ * F_;
    const size_t ePSz   = 320;
    const size_t wsBSz  = (size_t)16 * BF_;
    const size_t fixed_floats = mwSz + sspSz + psdCSz + featSz + ePSz + wsBSz;
    const size_t per_split = (size_t)NFT * B_ * PSD_J;

    const int cands[5] = {25, 10, 5, 2, 1};
    int nsp = 1;
    for (int ci = 0; ci < 5; ++ci) {
        size_t need = 4 * ((size_t)cands[ci] * per_split + fixed_floats);
        if (need <= ws_size) { nsp = cands[ci]; break; }
    }
    const int TL = T_ / nsp;

    float* mw      = w0;
    float* ssp     = mw + mwSz;
    float* psdC    = ssp + sspSz;
    float* feat    = psdC + psdCSz;
    float* eP      = feat + featSz;
    float* wsB     = eP + ePSz;
    float* psdPart = wsB + wsBSz;

    k0_mask<<<dim3(9, 8, 16), 256, 0, stream>>>(mss, msn, mw, ssp);
    k1b_psd<<<dim3(NFT, nsp, B_), 128, 0, stream>>>(dre, dim_, mw, psdPart, TL);
    k2a_sum<<<dim3(NFT, B_, 18), 256, 0, stream>>>(psdPart, psdC, nsp);
    k2f_feat<<<dim3(NFT, B_), 256, 0, stream>>>(psdC, ssp, feat);
    k2b_att<<<dim3(B_, C_, 5), 256, 0, stream>>>(feat, W, bp, wg, eP);
    k3_solve<<<dim3((BF_ + 31) / 32), 128, 0, stream>>>(psdC, eP, bg, wsB);
    k4_beam<<<dim3(9, 50, B_), 256, 0, stream>>>(dre, dim_, wsB, out);
}

// Round 6
// 661.727 us; speedup vs baseline: 1.3529x; 1.1200x over previous
//
#include <hip/hip_runtime.h>
#include <math.h>

#define B_ 8
#define T_ 1000
#define C_ 8
#define F_ 513
#define ATT_ 320
#define BF_ (B_*F_)          // 4104
#define NFT 9                // f-tiles of 64
#define PSD_J 9216           // 2s * 36p * 2ri * 64fl floats per (sp,b,ft)
#define TPAD 576             // mw row stride (9*64, 64B-aligned)
#define CF_ (C_*F_)

// ---------------- Kernel 0: mask channel-mean + transpose ----------------
// grid (9 ftile, 16 ttile, 16 = s*8+b), block 256. t-tile 64 -> LDS 16.9KB -> 8 blk/CU.
// Reads mask[b,f,c,t] (t-contiguous float4), mean over c, writes mw[s][b][t][f]
// (f-contiguous rows, TPAD stride). Speech blocks emit per-(b,ttile,f) t-sums.
__global__ __launch_bounds__(256) void k0_mask(
    const float* __restrict__ mss, const float* __restrict__ msn,
    float* __restrict__ mw, float* __restrict__ ssp)
{
    const int ftile = blockIdx.x, tt = blockIdx.y, z = blockIdx.z;
    const int s = z >> 3, b = z & 7;
    const float* __restrict__ src = s ? msn : mss;
    const int f0 = ftile * 64, t0 = tt * 64;
    const int tid = threadIdx.x;

    __shared__ float lt[64 * 66];    // [t_local][fa]
    __shared__ float red[256];

    // read persona: fa = freq-in-tile (0..63), tq = t-interleave (0..3)
    const int fa = tid >> 2, tq = tid & 3;
    float4 a[4];
#pragma unroll
    for (int k = 0; k < 4; ++k) a[k] = make_float4(0.f, 0.f, 0.f, 0.f);

    if ((f0 + fa) < F_) {
        const float* __restrict__ mp = src + (size_t)((b * F_ + f0 + fa) * C_) * T_;
#pragma unroll
        for (int c = 0; c < C_; ++c) {
#pragma unroll
            for (int k = 0; k < 4; ++k) {
                int tb = t0 + tq * 4 + k * 16;   // %4==0; tb<T_ -> full float4 valid
                if (tb < T_) {
                    float4 v = *(const float4*)&mp[(size_t)c * T_ + tb];
                    a[k].x += v.x; a[k].y += v.y; a[k].z += v.z; a[k].w += v.w;
                }
            }
        }
    }
#pragma unroll
    for (int k = 0; k < 4; ++k) {
        int tl0 = tq * 4 + k * 16;
        lt[(tl0 + 0) * 66 + fa] = a[k].x * 0.125f;
        lt[(tl0 + 1) * 66 + fa] = a[k].y * 0.125f;
        lt[(tl0 + 2) * 66 + fa] = a[k].z * 0.125f;
        lt[(tl0 + 3) * 66 + fa] = a[k].w * 0.125f;
    }
    __syncthreads();

    // write persona: fw = freq lane (0..63), tr = t-quarter (0..3)
    const int fw = tid & 63, tr = tid >> 6;
    float sum = 0.f;
#pragma unroll 4
    for (int tt2 = 0; tt2 < 16; ++tt2) {
        int tl_ = tr * 16 + tt2;
        float v = lt[tl_ * 66 + fw];
        sum += v;
        int tg_ = t0 + tl_;
        if (tg_ < T_)
            mw[((size_t)(s * B_ + b) * T_ + tg_) * TPAD + f0 + fw] = v;
    }
    if (s == 0) {
        red[tid] = sum;
        __syncthreads();
        if (tid < 64)
            ssp[(b * 16 + tt) * TPAD + f0 + tid] =
                red[tid] + red[64 + tid] + red[128 + tid] + red[192 + tid];
    }
}

// ---------------- Kernel 1b: PSD accumulation (no LDS, no barriers) ----------------
// grid (9, nsp, B), block 256 = 4 waves; wave w = pair-nonet w, lanes = 64 distinct f
// -> every load is a 256B wave-wide span; 4x duplication across waves hits L1.
__global__ __launch_bounds__(256) void k1b_psd(
    const float* __restrict__ dre, const float* __restrict__ dim_,
    const float* __restrict__ mw, float* __restrict__ psdPart, int TL)
{
    const int ft = blockIdx.x, sp = blockIdx.y, b = blockIdx.z;
    const int tid = threadIdx.x;
    const int fl = tid & 63, nb = tid >> 6;
    const int f0 = ft * 64;
    const int t0 = sp * TL;
    const bool fval = (f0 + fl) < F_;

    const float* __restrict__ pS = mw + ((size_t)b * T_ + t0) * TPAD + f0 + fl;
    const float* __restrict__ pN = mw + ((size_t)(B_ + b) * T_ + t0) * TPAD + f0 + fl;
    const float* __restrict__ pr = dre + (size_t)(b * T_ + t0) * CF_ + f0 + fl;
    const float* __restrict__ pi_ = dim_ + (size_t)(b * T_ + t0) * CF_ + f0 + fl;

    float aSr[9], aSi[9], aNr[9], aNi[9];
#pragma unroll
    for (int i = 0; i < 9; ++i) { aSr[i]=0.f; aSi[i]=0.f; aNr[i]=0.f; aNi[i]=0.f; }

#pragma unroll 2
    for (int t = 0; t < TL; ++t) {
        float m_s = *pS; float m_n = *pN;
        pS += TPAD; pN += TPAD;
        float xr[8], xi[8];
        if (fval) {
#pragma unroll
            for (int c = 0; c < 8; ++c) { xr[c] = pr[c * F_]; xi[c] = pi_[c * F_]; }
        } else {
#pragma unroll
            for (int c = 0; c < 8; ++c) { xr[c] = 0.f; xi[c] = 0.f; }
        }
        pr += CF_; pi_ += CF_;
#define PAIR(i,c,e) { float prd = xr[c]*xr[e] + xi[c]*xi[e]; \
                      float pim = xi[c]*xr[e] - xr[c]*xi[e]; \
                      aSr[i] += m_s*prd; aSi[i] += m_s*pim;  \
                      aNr[i] += m_n*prd; aNi[i] += m_n*pim; }
        if (nb == 0)      { PAIR(0,0,0) PAIR(1,0,1) PAIR(2,0,2) PAIR(3,0,3) PAIR(4,0,4) PAIR(5,0,5) PAIR(6,0,6) PAIR(7,0,7) PAIR(8,1,1) }
        else if (nb == 1) { PAIR(0,1,2) PAIR(1,1,3) PAIR(2,1,4) PAIR(3,1,5) PAIR(4,1,6) PAIR(5,1,7) PAIR(6,2,2) PAIR(7,2,3) PAIR(8,2,4) }
        else if (nb == 2) { PAIR(0,2,5) PAIR(1,2,6) PAIR(2,2,7) PAIR(3,3,3) PAIR(4,3,4) PAIR(5,3,5) PAIR(6,3,6) PAIR(7,3,7) PAIR(8,4,4) }
        else              { PAIR(0,4,5) PAIR(1,4,6) PAIR(2,4,7) PAIR(3,5,5) PAIR(4,5,6) PAIR(5,5,7) PAIR(6,6,6) PAIR(7,6,7) PAIR(8,7,7) }
#undef PAIR
    }

    if (fval) {
        size_t base = (size_t)((sp * B_ + b) * NFT + ft) * PSD_J;
#pragma unroll
        for (int i = 0; i < 9; ++i) {
            int p = nb * 9 + i;
            psdPart[base + ((0 * 36 + p) * 2 + 0) * 64 + fl] = aSr[i];
            psdPart[base + ((0 * 36 + p) * 2 + 1) * 64 + fl] = aSi[i];
            psdPart[base + ((1 * 36 + p) * 2 + 0) * 64 + fl] = aNr[i];
            psdPart[base + ((1 * 36 + p) * 2 + 1) * 64 + fl] = aNi[i];
        }
    }
}

// ---------------- Kernel 2a: flat partial reduction ----------------
// grid (9, B, 36) x 256 thr: one element of PSD_J per thread.
__global__ __launch_bounds__(256) void k2a_sum(
    const float* __restrict__ psdPart, float* __restrict__ psdC, int nsp)
{
    const int ft = blockIdx.x, b = blockIdx.y, ch = blockIdx.z;
    const int j = ch * 256 + threadIdx.x;
    const int fl = j & 63, mcode = j >> 6;
    float acc = 0.f;
    for (int sp = 0; sp < nsp; ++sp)
        acc += psdPart[(size_t)((sp * B_ + b) * NFT + ft) * PSD_J + j];
    if ((ft * 64 + fl) < F_)
        psdC[(size_t)mcode * BF_ + b * F_ + ft * 64 + fl] = acc;
}

// ---------------- Kernel 2f: attention features ----------------
// grid (9, B), block 512 = 64 f x 8 c.
__global__ __launch_bounds__(512) void k2f_feat(
    const float* __restrict__ psdC, const float* __restrict__ ssp,
    float* __restrict__ feat)
{
    const int ft = blockIdx.x, b = blockIdx.y;
    const int tid = threadIdx.x;
    const int f0 = ft * 64;
    __shared__ float pl[64 * 73];
    __shared__ float sl[64];

    for (int idx = tid; idx < 64 * 72; idx += 512) {
        int fl = idx & 63, mc = idx >> 6;          // mc = p*2+ri (speech block)
        float v = 0.f;
        if ((f0 + fl) < F_) v = psdC[(size_t)mc * BF_ + b * F_ + f0 + fl];
        pl[fl * 73 + mc] = v;
    }
    if (tid < 64) {
        float S = 0.f;
#pragma unroll
        for (int tt = 0; tt < 16; ++tt) S += ssp[(b * 16 + tt) * TPAD + f0 + tid];
        sl[tid] = S;
    }
    __syncthreads();

    const int fl2 = tid & 63, c = tid >> 6;
    const int f2 = f0 + fl2;
    if (f2 < F_) {
        float inv = 1.f / (7.f * (sl[fl2] + 1e-15f));
        float sr = 0.f, si = 0.f;
#pragma unroll
        for (int e = 0; e < 8; ++e) {
            if (e == c) continue;
            int r = c < e ? c : e, cc = c < e ? e : c;
            int p = 8 * r - (r * (r - 1)) / 2 + (cc - r);
            float vr = pl[fl2 * 73 + p * 2], vi = pl[fl2 * 73 + p * 2 + 1];
            sr += vr; si += (e > c) ? vi : -vi;
        }
        feat[(b * C_ + c) * F_ + f2] = sqrtf(sr * sr + si * si) * inv;
    }
}

// ---------------- Kernel 2b: attention MLP partials ----------------
// grid (B, C, 5): 64-wide a-tile per block; transposed W tile in LDS.
__global__ __launch_bounds__(256) void k2b_att(
    const float* __restrict__ feat, const float* __restrict__ W,
    const float* __restrict__ bp, const float* __restrict__ wg,
    float* __restrict__ ePart)
{
    const int b = blockIdx.x, c = blockIdx.y, at = blockIdx.z;
    const int a0 = at * 64;
    const int tid = threadIdx.x;
    __shared__ float featL[576];
    __shared__ float Wt[64 * 65];
    __shared__ float dsum[4][64];

    for (int i = tid; i < 576; i += 256)
        featL[i] = (i < F_) ? feat[(b * C_ + c) * F_ + i] : 0.f;

    const int al = tid & 63, q = tid >> 6;
    float partial = 0.f;
    for (int fc = 0; fc < F_; fc += 64) {
        __syncthreads();
#pragma unroll
        for (int i = 0; i < 16; ++i) {
            int item = tid + 256 * i;
            int fo = item & 63, a = item >> 6;
            int f = fc + fo;
            Wt[fo * 65 + a] = (f < F_) ? W[(size_t)(a0 + a) * F_ + f] : 0.f;
        }
        __syncthreads();
#pragma unroll
        for (int k = 0; k < 16; ++k) {
            int fo = q * 16 + k;
            partial += featL[fc + fo] * Wt[fo * 65 + al];
        }
    }
    dsum[q][al] = partial;
    __syncthreads();
    if (tid < 64) {
        float dot = dsum[0][tid] + dsum[1][tid] + dsum[2][tid] + dsum[3][tid] + bp[a0 + tid];
        float ep = tanhf(dot) * wg[a0 + tid];
#pragma unroll
        for (int off = 32; off >= 1; off >>= 1) ep += __shfl_xor(ep, off);
        if (tid == 0) ePart[(b * C_ + c) * 5 + at] = ep;
    }
}

// ---------------- Kernel 3: e-reduce + softmax(u) + MVDR solve -> conj(ws) ----------------
__global__ __launch_bounds__(128) void k3_solve(
    const float* __restrict__ psdC, const float* __restrict__ ePart,
    const float* __restrict__ bg, float* __restrict__ wsB)
{
    const int tid = threadIdx.x;
    const int sl_ = tid >> 2;
    const int j = tid & 3;
    int sysg = blockIdx.x * 32 + sl_;
    bool wv = sysg < BF_;
    int sys = wv ? sysg : BF_ - 1;
    __shared__ float aug[32 * 257];
    __shared__ float eL[64];
    __shared__ float uL[64];
    float* A = &aug[sl_ * 257];
#define AG(r,cl,ri) A[((((r)*16+(cl))<<1)+(ri))]

    if (tid < 64) {
        float e = bg[0];
#pragma unroll
        for (int z = 0; z < 5; ++z) e += ePart[tid * 5 + z];
        eL[tid] = e;
    }

#pragma unroll
    for (int r = 0; r < 8; ++r) {
#pragma unroll
        for (int ci2 = 0; ci2 < 4; ++ci2) {
            int col = j + ci2 * 4;
            int s = (col < 8) ? 1 : 0;            // A = psd_n, B = psd_s
            int c2 = (col < 8) ? col : col - 8;
            int rr = r < c2 ? r : c2, cc = r < c2 ? c2 : r;
            int p = 8 * rr - (rr * (rr - 1)) / 2 + (cc - rr);
            float re = psdC[(size_t)((s * 36 + p) * 2 + 0) * BF_ + sys];
            float im = psdC[(size_t)((s * 36 + p) * 2 + 1) * BF_ + sys];
            if (c2 < r) im = -im;
            AG(r, col, 0) = re; AG(r, col, 1) = im;
        }
    }
    __syncthreads();

    if (tid < 64) {
        int bb = tid >> 3;
        float m = -1e30f;
#pragma unroll
        for (int i = 0; i < 8; ++i) m = fmaxf(m, eL[bb * 8 + i]);
        float s = 0.f;
#pragma unroll
        for (int i = 0; i < 8; ++i) s += expf(2.f * (eL[bb * 8 + i] - m));
        uL[tid] = expf(2.f * (eL[tid] - m)) / s;
    }

    for (int k = 0; k < 8; ++k) {
        int rb = k; float bm = -1.f;
        for (int r = k; r < 8; ++r) {
            float m = fabsf(AG(r, k, 0)) + fabsf(AG(r, k, 1));
            if (m > bm) { bm = m; rb = r; }
        }
        if (rb != k) {
#pragma unroll
            for (int ci2 = 0; ci2 < 4; ++ci2) {
                int col = j + ci2 * 4;
                float t0_ = AG(k, col, 0), t1_ = AG(k, col, 1);
                AG(k, col, 0) = AG(rb, col, 0); AG(k, col, 1) = AG(rb, col, 1);
                AG(rb, col, 0) = t0_; AG(rb, col, 1) = t1_;
            }
        }
        __syncthreads();
        float dr = AG(k, k, 0), di = AG(k, k, 1);
        float dd = dr * dr + di * di;
        float pr = dr / dd, pi = -di / dd;
        for (int r = k + 1; r < 8; ++r) {
            float ar = AG(r, k, 0), ai = AG(r, k, 1);
            float fr = ar * pr - ai * pi, fi = ar * pi + ai * pr;
#pragma unroll
            for (int ci2 = 0; ci2 < 4; ++ci2) {
                int col = j + ci2 * 4;
                if (col > k) {
                    float xr_ = AG(k, col, 0), xi_ = AG(k, col, 1);
                    AG(r, col, 0) -= fr * xr_ - fi * xi_;
                    AG(r, col, 1) -= fr * xi_ + fi * xr_;
                }
            }
        }
        __syncthreads();
    }

#pragma unroll
    for (int bc2 = 0; bc2 < 2; ++bc2) {
        int bc = j + 8 + bc2 * 4;
        for (int k = 7; k >= 0; --k) {
            float vr = AG(k, bc, 0), vi = AG(k, bc, 1);
            for (int r = k + 1; r < 8; ++r) {
                float ar = AG(k, r, 0), ai = AG(k, r, 1);
                float xr_ = AG(r, bc, 0), xi_ = AG(r, bc, 1);
                vr -= ar * xr_ - ai * xi_;
                vi -= ar * xi_ + ai * xr_;
            }
            float dr = AG(k, k, 0), di = AG(k, k, 1);
            float dd = dr * dr + di * di;
            float pr = dr / dd, pi = -di / dd;
            float tr_ = vr * pr - vi * pi;
            float ti_ = vr * pi + vi * pr;
            AG(k, bc, 0) = tr_; AG(k, bc, 1) = ti_;
        }
    }
    __syncthreads();

    float trr = 1e-15f, tri = 0.f;
#pragma unroll
    for (int i = 0; i < 8; ++i) { trr += AG(i, 8 + i, 0); tri += AG(i, 8 + i, 1); }
    float tdd = trr * trr + tri * tri;
    int b = sys / F_;
#pragma unroll
    for (int e2 = 0; e2 < 2; ++e2) {
        int e = j + e2 * 4;
        float nr = 0.f, ni = 0.f;
#pragma unroll
        for (int cch = 0; cch < 8; ++cch) {
            float uu = uL[b * 8 + cch];
            nr += AG(e, 8 + cch, 0) * uu;
            ni += AG(e, 8 + cch, 1) * uu;
        }
        float wr = (nr * trr + ni * tri) / tdd;
        float wi = (ni * trr - nr * tri) / tdd;
        if (wv) {
            wsB[(e * 2 + 0) * BF_ + sysg] = wr;    // store conj(ws)
            wsB[(e * 2 + 1) * BF_ + sysg] = -wi;
        }
    }
#undef AG
}

// ---------------- Kernel 4: beamform + transpose to (B,T,F) ----------------
// grid (9, 50, B), block 256 = 64 f-lanes x 4 t-groups; 5 t per thread.
__global__ __launch_bounds__(256) void k4_beam(
    const float* __restrict__ dre, const float* __restrict__ dim_,
    const float* __restrict__ wsB, float* __restrict__ out)
{
    const int ft = blockIdx.x, tt = blockIdx.y, b = blockIdx.z;
    const int tid = threadIdx.x;
    const int fl = tid & 63, tg = tid >> 6;
    const int f = ft * 64 + fl;
    if (f >= F_) return;
    const int bf = b * F_ + f;
    float cr[8], ci[8];
#pragma unroll
    for (int c = 0; c < 8; ++c) {
        cr[c] = wsB[(c * 2 + 0) * BF_ + bf];
        ci[c] = wsB[(c * 2 + 1) * BF_ + bf];
    }
#pragma unroll
    for (int k = 0; k < 5; ++k) {
        int t = tt * 20 + tg * 5 + k;
        size_t base = (size_t)(b * T_ + t) * CF_ + f;
        float aR = 0.f, aI = 0.f;
#pragma unroll
        for (int c = 0; c < 8; ++c) {
            float xr = dre[base + c * F_], xi = dim_[base + c * F_];
            aR += cr[c] * xr - ci[c] * xi;
            aI += cr[c] * xi + ci[c] * xr;
        }
        out[(size_t)(b * T_ + t) * F_ + f] = aR;
        out[(size_t)B_ * T_ * F_ + (size_t)(b * T_ + t) * F_ + f] = aI;
    }
}

extern "C" void kernel_launch(void* const* d_in, const int* in_sizes, int n_in,
                              void* d_out, int out_size, void* d_ws, size_t ws_size,
                              hipStream_t stream)
{
    const float* dre = (const float*)d_in[0];
    const float* dim_ = (const float*)d_in[1];
    const float* mss = (const float*)d_in[2];
    const float* msn = (const float*)d_in[3];
    const float* W  = (const float*)d_in[4];
    const float* bp = (const float*)d_in[5];
    const float* wg = (const float*)d_in[6];
    const float* bg = (const float*)d_in[7];
    float* out = (float*)d_out;
    float* w0 = (float*)d_ws;

    const size_t mwSz   = (size_t)2 * B_ * T_ * TPAD;
    const size_t sspSz  = (size_t)B_ * 16 * TPAD;
    const size_t psdCSz = (size_t)144 * BF_;
    const size_t featSz = (size_t)B_ * C_ * F_;
    const size_t ePSz   = 320;
    const size_t wsBSz  = (size_t)16 * BF_;
    const size_t fixed_floats = mwSz + sspSz + psdCSz + featSz + ePSz + wsBSz;
    const size_t per_split = (size_t)NFT * B_ * PSD_J;

    const int cands[5] = {25, 10, 5, 2, 1};
    int nsp = 1;
    for (int ci = 0; ci < 5; ++ci) {
        size_t need = 4 * ((size_t)cands[ci] * per_split + fixed_floats);
        if (need <= ws_size) { nsp = cands[ci]; break; }
    }
    const int TL = T_ / nsp;

    float* mw      = w0;
    float* ssp     = mw + mwSz;
    float* psdC    = ssp + sspSz;
    float* feat    = psdC + psdCSz;
    float* eP      = feat + featSz;
    float* wsB     = eP + ePSz;
    float* psdPart = wsB + wsBSz;

    k0_mask<<<dim3(9, 16, 16), 256, 0, stream>>>(mss, msn, mw, ssp);
    k1b_psd<<<dim3(NFT, nsp, B_), 256, 0, stream>>>(dre, dim_, mw, psdPart, TL);
    k2a_sum<<<dim3(NFT, B_, 36), 256, 0, stream>>>(psdPart, psdC, nsp);
    k2f_feat<<<dim3(NFT, B_), 512, 0, stream>>>(psdC, ssp, feat);
    k2b_att<<<dim3(B_, C_, 5), 256, 0, stream>>>(feat, W, bp, wg, eP);
    k3_solve<<<dim3((BF_ + 31) / 32), 128, 0, stream>>>(psdC, eP, bg, wsB);
    k4_beam<<<dim3(9, 50, B_), 256, 0, stream>>>(dre, dim_, wsB, out);
}